// Round 9
// baseline (264.312 us; speedup 1.0000x reference)
//
#include <hip/hip_runtime.h>
#include <hip/hip_bf16.h>
#include <math.h>

typedef __bf16 bf16;
typedef bf16 bf16x2 __attribute__((ext_vector_type(2)));
typedef bf16 bf16x4 __attribute__((ext_vector_type(4)));
typedef bf16 bf16x8 __attribute__((ext_vector_type(8)));
typedef float f32x4 __attribute__((ext_vector_type(4)));
typedef float f32x16 __attribute__((ext_vector_type(16)));
typedef unsigned int uint;
typedef uint uint32x4 __attribute__((ext_vector_type(4)));

#define MFMA16(a, b, c) __builtin_amdgcn_mfma_f32_16x16x32_bf16((a), (b), (c), 0, 0, 0)
#define MFMA32(a, b, c) __builtin_amdgcn_mfma_f32_32x32x16_bf16((a), (b), (c), 0, 0, 0)

// q pre-scale: 1/sqrt(64) * log2(e), folded into QKV epilogue so attention
// can use raw v_exp_f32 (exp2) with no per-score multiply.
#define QSCALE 0.18033688011112042f

// async global->LDS, 16B per lane. LDS dest is wave-uniform base + lane*16
// (linear); global src is per-lane (carries the swizzle).
__device__ __forceinline__ void async16(const void* g, void* l) {
  __builtin_amdgcn_global_load_lds(
      (const __attribute__((address_space(1))) void*)g,
      (__attribute__((address_space(3))) void*)l, 16, 0, 0);
}

// pack 2 f32 -> bf16x2 word (compiler fuses to v_cvt_pk_bf16_f32)
__device__ __forceinline__ uint pkbf(float a, float b) {
  bf16x2 t = {(bf16)a, (bf16)b};
  return __builtin_bit_cast(uint, t);
}

// v_permlane32_swap_b32: x' = (lane<32 ? x : y_from_lane-32);
//                        y' = (lane<32 ? x_from_lane+32 : y)
__device__ __forceinline__ void pls(uint& x, uint& y) {
  asm volatile("v_permlane32_swap_b32 %0, %1" : "+v"(x), "+v"(y));
}

// ---------------- fp32 -> bf16 conversion, all three tensors in one launch ----
__global__ __launch_bounds__(256) void f2b_all_kernel(const float* __restrict__ x,
                                                      const float* __restrict__ wqkv,
                                                      const float* __restrict__ wproj,
                                                      bf16* __restrict__ xb,
                                                      bf16* __restrict__ wqb,
                                                      bf16* __restrict__ wpb) {
  int t = blockIdx.x * 256 + threadIdx.x;  // 0 .. 5M-1
  const float* in;
  bf16* out;
  int i;
  if (t < 4194304) {            // x: 16M elems
    in = x; out = xb; i = t * 4;
  } else if (t < 4980736) {     // wqkv: 3M elems
    in = wqkv; out = wqb; i = (t - 4194304) * 4;
  } else {                      // wproj: 1M elems
    in = wproj; out = wpb; i = (t - 4980736) * 4;
  }
  f32x4 v = *(const f32x4*)(in + i);
  bf16x4 o = {(bf16)v[0], (bf16)v[1], (bf16)v[2], (bf16)v[3]};
  *(bf16x4*)(out + i) = o;
}

// ---------------- axial RoPE cos/sin table: [n=1024][d=32] ----------------
__global__ __launch_bounds__(256) void table_kernel(float* __restrict__ cosT,
                                                    float* __restrict__ sinT) {
  int idx = blockIdx.x * 256 + threadIdx.x;
  if (idx >= 1024 * 32) return;
  int n = idx >> 5, d = idx & 31;
  int hf = n >> 5, wf = n & 31;
  int bi = (d & 15) >> 1;
  float base = (1.0f + 73.0f * bi) * 3.14159265358979323846f;  // linspace(1,512,8)[i]*pi
  int p = (d < 16) ? hf : wf;
  float pos = (2.0f * (float)p - 31.0f) * (1.0f / 31.0f);      // linspace(-1,1,32)
  float f = pos * base;
  cosT[idx] = cosf(f);
  sinT[idx] = sinf(f);
}

// ---------------- 256x256 8-wave GEMM, 16-phase BK=64 pipeline (race-fixed) ----
// A: MxK row-major, W: NxK row-major. Phase = one K-tile of 64 (16 phases).
// LDS: 2-slot double buffer, A/B each [2][256x64] (128KB total, 1 block/CU).
// Phase p: stage slot (p+1)&1 = tile p+1 (8 async16), s_waitcnt vmcnt(8)
// [counted: retires current slot's 8 loads (oldest); next 8 stay in flight],
// barrier, TWO sequential K=32 half-steps {12 b128 frag reads + 32 MFMA}
// (s=1 reads are independent of s=0 MFMAs -> compiler lgkmcnt overlap),
// TRAILING barrier.
// R8 POST-MORTEM (correctness fail, absmax 0.147): with 2 slots and ONE
// barrier/phase, stage(p+1) at the next iteration overwrites the slot
// compute(p) read, with no intervening barrier -> WAR race (a fast wave's DMA
// lands while a slow wave still reads). The trailing barrier is the WAR fence
// (R3's 2-slot pattern, which passed correctness). 31 barriers total (vs R4's
// 32), 16 vmcnt waits (vs 32), 8-load stage batches, intra-phase overlap.
// REGISTER NOTE: must stay at __launch_bounds__(512,2) — acc[8][4] = 128 AGPR
// + ~112 VGPR. (512,4) spills acc to scratch (R3: 12x slowdown).
// Swizzle (128B rows, 8x16B groups): LDS (row,g) holds global group g^(row&7);
// read applies same XOR (pre-swizzled global source, linear LDS dest);
// measured 0 conflicts with this exact pattern (R5).
// Block map: XCD j owns bm stripe [8j,8j+8); 4x4 squares inside the stripe.
// EPI 0: QKV epilogue (RoPE on q,k; q pre-scaled; v transposed), NBN=12
// EPI 1: proj epilogue (bias add, fp32 out), NBN=4
template <int EPI, int NBN>
__global__ __launch_bounds__(512, 2) void gemm_bt(
    const bf16* __restrict__ A, const bf16* __restrict__ W,
    bf16* __restrict__ oq, bf16* __restrict__ okk, bf16* __restrict__ ovt,
    const float* __restrict__ cosT, const float* __restrict__ sinT,
    float* __restrict__ outF, const float* __restrict__ bias) {
  constexpr int K = 1024;
  __shared__ bf16 As[2][256 * 64];
  __shared__ bf16 Bs[2][256 * 64];

  const int tid = threadIdx.x;
  const int lane = tid & 63;
  const int wid = tid >> 6;          // 0..7
  const int lo = lane & 15, hi = lane >> 4;
  const int wm = wid >> 2;           // 0..1 (M half)
  const int wn = wid & 3;            // 0..3 (N quarter)

  // XCD-stripe block mapping with 4x4 square ordering inside the stripe.
  const int wg = blockIdx.x;
  const int xcd = wg & 7;
  const int i = wg >> 3;             // 0 .. 8*NBN-1
  const int s4 = i >> 4;             // square index
  const int r4 = i & 15;
  const int bm = xcd * 8 + (s4 & 1) * 4 + (r4 & 3);
  const int bn = (s4 >> 1) * 4 + (r4 >> 2);

  const bf16* Ab = A + (size_t)bm * 256 * K;
  const bf16* Wb = W + (size_t)bn * 256 * K;

  const f32x4 fzero = {0.f, 0.f, 0.f, 0.f};
  f32x4 acc[8][4];
#pragma unroll
  for (int i2 = 0; i2 < 8; ++i2)
#pragma unroll
    for (int j = 0; j < 4; ++j) acc[i2][j] = fzero;

  // ---- staging: 4 x 16B chunks per thread per matrix per slot ----
  // chunk c = i2*512 + tid -> row = c>>3, group g = c&7 (16B units);
  // source group = g ^ (row&7) (pre-swizzled source, linear LDS dest).
  size_t srcOff[4];
  int ldsOff[4];
#pragma unroll
  for (int i2 = 0; i2 < 4; ++i2) {
    const int c = i2 * 512 + tid;
    const int row = c >> 3, g = c & 7;
    const int gsrc = g ^ (row & 7);
    srcOff[i2] = (size_t)row * K + gsrc * 8;
    ldsOff[i2] = c * 8;
  }

  auto stageSlot = [&](int slot, int kt) {
#pragma unroll
    for (int i2 = 0; i2 < 4; ++i2)
      async16(Ab + srcOff[i2] + kt * 64, &As[slot][ldsOff[i2]]);
#pragma unroll
    for (int i2 = 0; i2 < 4; ++i2)
      async16(Wb + srcOff[i2] + kt * 64, &Bs[slot][ldsOff[i2]]);
  };

  auto compute = [&](int slot) {
#pragma unroll
    for (int s = 0; s < 2; ++s) {
      bf16x8 af[8], bf[4];
#pragma unroll
      for (int mf = 0; mf < 8; ++mf) {
        const int row = wm * 128 + mf * 16 + lo;
        const int g = (s * 4 + hi) ^ (row & 7);
        af[mf] = *(const bf16x8*)&As[slot][row * 64 + g * 8];
      }
#pragma unroll
      for (int nf = 0; nf < 4; ++nf) {
        const int row = wn * 64 + nf * 16 + lo;
        const int g = (s * 4 + hi) ^ (row & 7);
        bf[nf] = *(const bf16x8*)&Bs[slot][row * 64 + g * 8];
      }
      __builtin_amdgcn_s_setprio(1);
#pragma unroll
      for (int mf = 0; mf < 8; ++mf)
#pragma unroll
        for (int nf = 0; nf < 4; ++nf)
          acc[mf][nf] = MFMA16(af[mf], bf[nf], acc[mf][nf]);
      __builtin_amdgcn_s_setprio(0);
    }
  };

  // prologue: slot 0 = tile 0 in flight (8 loads)
  stageSlot(0, 0);

  // phases p = 0..14: stage tile p+1, retire tile p's loads, barrier, compute,
  // trailing WAR barrier (next phase's stage overwrites slot p&1).
  for (int p = 0; p < 15; ++p) {
    stageSlot((p + 1) & 1, p + 1);
    asm volatile("s_waitcnt vmcnt(8)" ::: "memory");
    __builtin_amdgcn_s_barrier();
    compute(p & 1);
    __builtin_amdgcn_s_barrier();
  }
  // phase 15 (no further stage)
  asm volatile("s_waitcnt vmcnt(0)" ::: "memory");
  __builtin_amdgcn_s_barrier();
  compute(1);

  const int rb0 = bm * 256 + wm * 128;
  const int jb0 = bn * 256 + wn * 64;

  if constexpr (EPI == 0) {
#pragma unroll
    for (int ac = 0; ac < 4; ++ac) {
      const int j = jb0 + ac * 16 + lo;
      const int which = j >> 10;        // 0=q 1=k 2=v (uniform per wave)
      const int f = j & 1023;
      const int h = f >> 6, d = f & 63; // d = ac*16+lo; d<32 <=> ac<2
#pragma unroll
      for (int ar = 0; ar < 8; ++ar) {
        const int rb = rb0 + ar * 16 + 4 * hi;
        f32x4 v = acc[ar][ac];
        if (which == 2) {
          // v transposed: vt[(b*16+h)*64 + d][n], 4 consecutive n -> 8B store
          const int b = rb >> 10, n0 = rb & 1023;
          bf16x4 pk = {(bf16)v[0], (bf16)v[1], (bf16)v[2], (bf16)v[3]};
          *(bf16x4*)(ovt + ((size_t)((b * 16 + h) * 64 + d)) * 1024 + n0) = pk;
        } else {
          bf16* dst = which ? okk : oq;
          const float sc = which ? 1.0f : QSCALE;
#pragma unroll
          for (int reg = 0; reg < 4; ++reg) {
            const int r2 = rb + reg;
            const int b = r2 >> 10, n = r2 & 1023;
            float val = v[reg];
            float res;
            if (d < 32) {
              float c = cosT[n * 32 + d];
              float sn = sinT[n * 32 + d];
              float pp = __shfl_xor(val, 1);  // rotary partner: adjacent lane = d^1
              res = (d & 1) ? fmaf(val, c, pp * sn) : fmaf(val, c, -(pp * sn));
            } else {
              res = val;
            }
            dst[((size_t)((b * 16 + h) * 1024 + n)) * 64 + d] = (bf16)(res * sc);
          }
        }
      }
    }
  } else {
#pragma unroll
    for (int ac = 0; ac < 4; ++ac) {
      const int j = jb0 + ac * 16 + lo;
      const float bv = bias[j];
#pragma unroll
      for (int ar = 0; ar < 8; ++ar) {
        const int rb = rb0 + ar * 16 + 4 * hi;
#pragma unroll
        for (int reg = 0; reg < 4; ++reg)
          outF[(size_t)(rb + reg) * 1024 + j] = acc[ar][ac][reg] + bv;
      }
    }
  }
}

// ---------------- flash attention v3: 32x32 MFMA, swapped QK^T, P in registers --
// (unchanged from round 7 — verified: total dropped 273->254us with this)
__global__ __launch_bounds__(512, 4) void attn_fwd(const bf16* __restrict__ q,
                                                   const bf16* __restrict__ k,
                                                   const bf16* __restrict__ vt,
                                                   bf16* __restrict__ o) {
  __shared__ bf16 Kt[2][64 * 64];
  __shared__ bf16 Vt[2][64 * 64];
  __shared__ float Psm[8][32];
  const int tid = threadIdx.x;
  const int lane = tid & 63, wid = tid >> 6;
  const int l31 = lane & 31;
  const int s = lane >> 5;          // half-wave index
  const int m7 = l31 & 7;
  const int j = blockIdx.x;                  // 0..1023
  const int bh = (j & 7) + ((j >> 5) << 3);  // 0..255
  const int qt = (j >> 3) & 3;               // 0..3
  const bf16* qg = q + (size_t)bh * 65536;
  const bf16* kg = k + (size_t)bh * 65536;
  const bf16* vg = vt + (size_t)bh * 65536;

  // Q as B-frags: qf[kb4] elem j = Q[qrow][16*kb4 + 8*s + j]
  const int qrow = qt * 256 + wid * 32 + l31;
  bf16x8 qf[4];
#pragma unroll
  for (int kb4 = 0; kb4 < 4; ++kb4)
    qf[kb4] = *(const bf16x8*)(qg + (size_t)qrow * 64 + kb4 * 16 + s * 8);

  const int srow = tid >> 3;
  const int sgsrc = (tid & 7) ^ (srow & 7);
  auto stageKV = [&](int buf, int kv) {
    async16(kg + (size_t)(kv * 64 + srow) * 64 + sgsrc * 8, &Kt[buf][tid * 8]);
    async16(vg + (size_t)srow * 1024 + kv * 64 + sgsrc * 8, &Vt[buf][tid * 8]);
  };

  // drain qf loads so the async vmcnt bookkeeping below is exact
  asm volatile("s_waitcnt vmcnt(0)" ::: "memory");
  stageKV(0, 0);

  f32x16 of0 = {0.f, 0.f, 0.f, 0.f, 0.f, 0.f, 0.f, 0.f,
                0.f, 0.f, 0.f, 0.f, 0.f, 0.f, 0.f, 0.f};
  f32x16 of1 = of0;
  float psum = 0.f;

  for (int kv = 0; kv < 16; ++kv) {
    const int cur = kv & 1;
    if (kv < 15) {
      stageKV(cur ^ 1, kv + 1);
      asm volatile("s_waitcnt vmcnt(2)" ::: "memory");
    } else {
      asm volatile("s_waitcnt vmcnt(0)" ::: "memory");
    }
    __builtin_amdgcn_s_barrier();

    // S^T = K Q (swapped): z0 = keys 0..31, z1 = keys 32..63 (this tile)
    f32x16 z0 = {0.f, 0.f, 0.f, 0.f, 0.f, 0.f, 0.f, 0.f,
                 0.f, 0.f, 0.f, 0.f, 0.f, 0.f, 0.f, 0.f};
    f32x16 z1 = z0;
#pragma unroll
    for (int kb4 = 0; kb4 < 4; ++kb4) {
      bf16x8 k0 = *(const bf16x8*)&Kt[cur][l31 * 64 + (((2 * kb4 + s) ^ m7) * 8)];
      bf16x8 k1 = *(const bf16x8*)&Kt[cur][(32 + l31) * 64 + (((2 * kb4 + s) ^ m7) * 8)];
      z0 = MFMA32(k0, qf[kb4], z0);
      z1 = MFMA32(k1, qf[kb4], z1);
    }

    // P = exp2(S^T) in-register; pack pairs (regs 2m,2m+1 = consecutive keys)
    uint c0[8], c1[8];
#pragma unroll
    for (int m = 0; m < 8; ++m) {
      float a0 = __builtin_amdgcn_exp2f(z0[2 * m]);
      float b0 = __builtin_amdgcn_exp2f(z0[2 * m + 1]);
      float a1 = __builtin_amdgcn_exp2f(z1[2 * m]);
      float b1 = __builtin_amdgcn_exp2f(z1[2 * m + 1]);
      psum += (a0 + b0) + (a1 + b1);
      c0[m] = pkbf(a0, b0);
      c1[m] = pkbf(a1, b1);
    }

    // O += P V: per 16-key block kb, regroup P into A-frag via 2 permlane swaps
    auto pv = [&](uint* cc, int bb, int kb) {
      uint w0 = cc[4 * bb], w2 = cc[4 * bb + 2];
      uint w1 = cc[4 * bb + 1], w3 = cc[4 * bb + 3];
      pls(w0, w2);
      pls(w1, w3);
      uint32x4 W = {w0, w1, w2, w3};
      bf16x8 apv = __builtin_bit_cast(bf16x8, W);
      bf16x8 vb0 = *(const bf16x8*)&Vt[cur][l31 * 64 + (((2 * kb + s) ^ m7) * 8)];
      bf16x8 vb1 = *(const bf16x8*)&Vt[cur][(32 + l31) * 64 + (((2 * kb + s) ^ m7) * 8)];
      of0 = MFMA32(apv, vb0, of0);
      of1 = MFMA32(apv, vb1, of1);
    };
    pv(c0, 0, 0);
    pv(c0, 1, 1);
    pv(c1, 0, 2);
    pv(c1, 1, 3);

    __syncthreads();  // all waves done reading cur before next stage overwrites
  }

  // psum: lane l and l+32 hold partials for the same q = l&31
  psum += __shfl_xor(psum, 32);
  const float inv = 1.0f / psum;
  if (lane < 32) Psm[wid][l31] = inv;
  __syncthreads();

  // write attnout as (b, n, h*64+d) bf16; C/D row r -> q = (r&3)+8*(r>>2)+4*s
  const int b = bh >> 4, h = bh & 15;
#pragma unroll
  for (int r = 0; r < 16; ++r) {
    const int qr = (r & 3) + 8 * (r >> 2) + 4 * s;
    const float iv = Psm[wid][qr];
    const int n = qt * 256 + wid * 32 + qr;
    const size_t base = ((size_t)(b * 1024 + n)) * 1024 + h * 64 + l31;
    o[base] = (bf16)(of0[r] * iv);
    o[base + 32] = (bf16)(of1[r] * iv);
  }
}

extern "C" void kernel_launch(void* const* d_in, const int* in_sizes, int n_in,
                              void* d_out, int out_size, void* d_ws, size_t ws_size,
                              hipStream_t stream) {
  (void)in_sizes; (void)n_in; (void)out_size; (void)ws_size;
  const float* x = (const float*)d_in[0];
  const float* wqkv = (const float*)d_in[1];
  const float* wproj = (const float*)d_in[2];
  const float* bproj = (const float*)d_in[3];

  char* ws = (char*)d_ws;
  bf16* xb = (bf16*)(ws);                  // 33554432 B (x bf16; reused as attnout)
  bf16* wqb = (bf16*)(ws + 33554432);      // 6291456 B
  bf16* wpb = (bf16*)(ws + 39845888);      // 2097152 B
  float* cosT = (float*)(ws + 41943040);   // 131072 B
  float* sinT = (float*)(ws + 42074112);   // 131072 B
  bf16* qb = (bf16*)(ws + 42205184);       // 33554432 B  (b,h,n,d), pre-scaled
  bf16* kb = (bf16*)(ws + 75759616);       // 33554432 B  (b,h,n,d)
  bf16* vtb = (bf16*)(ws + 109314048);     // 33554432 B  (b,h,d,n)
  // total ws use: 142868480 B

  // all three f32->bf16 conversions in one launch: 5M threads
  f2b_all_kernel<<<20480, 256, 0, stream>>>(x, wqkv, wproj, xb, wqb, wpb);
  table_kernel<<<128, 256, 0, stream>>>(cosT, sinT);

  // QKV: M=16384, N=3072, K=1024 -> 64 bm x 12 bn = 768 blocks of 256x256
  gemm_bt<0, 12><<<768, 512, 0, stream>>>(xb, wqb, qb, kb, vtb, cosT, sinT,
                                          nullptr, nullptr);
  // attention: 1024 blocks (4 q-tiles x 256 heads, XCD-chunked), 8 waves each
  attn_fwd<<<1024, 512, 0, stream>>>(qb, kb, vtb, xb);
  // proj: M=16384, N=1024, K=1024 -> 64 bm x 4 bn = 256 blocks
  gemm_bt<1, 4><<<256, 512, 0, stream>>>(xb, wpb, nullptr, nullptr, nullptr,
                                         nullptr, nullptr, (float*)d_out, bproj);
}

// Round 10
// 258.148 us; speedup vs baseline: 1.0239x; 1.0239x over previous
//
#include <hip/hip_runtime.h>
#include <hip/hip_bf16.h>
#include <math.h>

typedef __bf16 bf16;
typedef bf16 bf16x2 __attribute__((ext_vector_type(2)));
typedef bf16 bf16x4 __attribute__((ext_vector_type(4)));
typedef bf16 bf16x8 __attribute__((ext_vector_type(8)));
typedef float f32x4 __attribute__((ext_vector_type(4)));
typedef float f32x16 __attribute__((ext_vector_type(16)));
typedef unsigned int uint;
typedef uint uint32x4 __attribute__((ext_vector_type(4)));

#define MFMA16(a, b, c) __builtin_amdgcn_mfma_f32_16x16x32_bf16((a), (b), (c), 0, 0, 0)
#define MFMA32(a, b, c) __builtin_amdgcn_mfma_f32_32x32x16_bf16((a), (b), (c), 0, 0, 0)

// q pre-scale: 1/sqrt(64) * log2(e), folded into QKV epilogue so attention
// can use raw v_exp_f32 (exp2) with no per-score multiply.
#define QSCALE 0.18033688011112042f

// async global->LDS, 16B per lane. LDS dest is wave-uniform base + lane*16
// (linear); global src is per-lane (carries the swizzle).
__device__ __forceinline__ void async16(const void* g, void* l) {
  __builtin_amdgcn_global_load_lds(
      (const __attribute__((address_space(1))) void*)g,
      (__attribute__((address_space(3))) void*)l, 16, 0, 0);
}

// pack 2 f32 -> bf16x2 word (compiler fuses to v_cvt_pk_bf16_f32)
__device__ __forceinline__ uint pkbf(float a, float b) {
  bf16x2 t = {(bf16)a, (bf16)b};
  return __builtin_bit_cast(uint, t);
}

// v_permlane32_swap_b32: x' = (lane<32 ? x : y_from_lane-32);
//                        y' = (lane<32 ? x_from_lane+32 : y)
__device__ __forceinline__ void pls(uint& x, uint& y) {
  asm volatile("v_permlane32_swap_b32 %0, %1" : "+v"(x), "+v"(y));
}

// ---------------- fp32 -> bf16 conversion, all three tensors in one launch ----
__global__ __launch_bounds__(256) void f2b_all_kernel(const float* __restrict__ x,
                                                      const float* __restrict__ wqkv,
                                                      const float* __restrict__ wproj,
                                                      bf16* __restrict__ xb,
                                                      bf16* __restrict__ wqb,
                                                      bf16* __restrict__ wpb) {
  int t = blockIdx.x * 256 + threadIdx.x;  // 0 .. 5M-1
  const float* in;
  bf16* out;
  int i;
  if (t < 4194304) {            // x: 16M elems
    in = x; out = xb; i = t * 4;
  } else if (t < 4980736) {     // wqkv: 3M elems
    in = wqkv; out = wqb; i = (t - 4194304) * 4;
  } else {                      // wproj: 1M elems
    in = wproj; out = wpb; i = (t - 4980736) * 4;
  }
  f32x4 v = *(const f32x4*)(in + i);
  bf16x4 o = {(bf16)v[0], (bf16)v[1], (bf16)v[2], (bf16)v[3]};
  *(bf16x4*)(out + i) = o;
}

// ---------------- axial RoPE cos/sin table: [n=1024][d=32] ----------------
__global__ __launch_bounds__(256) void table_kernel(float* __restrict__ cosT,
                                                    float* __restrict__ sinT) {
  int idx = blockIdx.x * 256 + threadIdx.x;
  if (idx >= 1024 * 32) return;
  int n = idx >> 5, d = idx & 31;
  int hf = n >> 5, wf = n & 31;
  int bi = (d & 15) >> 1;
  float base = (1.0f + 73.0f * bi) * 3.14159265358979323846f;  // linspace(1,512,8)[i]*pi
  int p = (d < 16) ? hf : wf;
  float pos = (2.0f * (float)p - 31.0f) * (1.0f / 31.0f);      // linspace(-1,1,32)
  float f = pos * base;
  cosT[idx] = cosf(f);
  sinT[idx] = sinf(f);
}

// ---------------- 256x256 8-wave GEMM, 32-phase counted-vmcnt pipeline ----------
// VERIFIED BEST (R4/R6/R7: QKV 127.8us, MfmaUtil 34%, VGPR 112, conflicts 0).
// R3: (512,4) spills acc -> 12x slowdown. R5: 8-phase port regressed (short K).
// R8: 2-slot/1-barrier raced (WAR). R9: 2-slot/2-barrier BK=64 = 140us (slower).
// GEMM K-loop is declared structurally plateaued — do not re-attempt.
template <int EPI, int NBN>
__global__ __launch_bounds__(512, 2) void gemm_bt(
    const bf16* __restrict__ A, const bf16* __restrict__ W,
    bf16* __restrict__ oq, bf16* __restrict__ okk, bf16* __restrict__ ovt,
    const float* __restrict__ cosT, const float* __restrict__ sinT,
    float* __restrict__ outF, const float* __restrict__ bias) {
  constexpr int K = 1024;
  __shared__ bf16 As[4][256 * 32];
  __shared__ bf16 Bs[4][256 * 32];

  const int tid = threadIdx.x;
  const int lane = tid & 63;
  const int wid = tid >> 6;          // 0..7
  const int lo = lane & 15, hi = lane >> 4;
  const int wm = wid >> 2;           // 0..1 (M half)
  const int wn = wid & 3;            // 0..3 (N quarter)

  // XCD-stripe block mapping with 4x4 square ordering inside the stripe.
  const int wg = blockIdx.x;
  const int xcd = wg & 7;
  const int i = wg >> 3;             // 0 .. 8*NBN-1
  const int s = i >> 4;              // square index
  const int r = i & 15;
  const int bm = xcd * 8 + (s & 1) * 4 + (r & 3);
  const int bn = (s >> 1) * 4 + (r >> 2);

  const bf16* Ab = A + (size_t)bm * 256 * K;
  const bf16* Wb = W + (size_t)bn * 256 * K;

  const f32x4 fzero = {0.f, 0.f, 0.f, 0.f};
  f32x4 acc[8][4];
#pragma unroll
  for (int i2 = 0; i2 < 8; ++i2)
#pragma unroll
    for (int j = 0; j < 4; ++j) acc[i2][j] = fzero;

  size_t srcOff[2];
  int ldsOff[2];
#pragma unroll
  for (int i2 = 0; i2 < 2; ++i2) {
    const int c = i2 * 512 + tid;
    const int row = c >> 2, g = c & 3;
    const int gsrc = g ^ ((row >> 1) & 3);
    srcOff[i2] = (size_t)row * K + gsrc * 8;
    ldsOff[i2] = c * 8;
  }

  auto stageSlot = [&](int slot, int kh) {
#pragma unroll
    for (int i2 = 0; i2 < 2; ++i2)
      async16(Ab + srcOff[i2] + kh * 32, &As[slot][ldsOff[i2]]);
#pragma unroll
    for (int i2 = 0; i2 < 2; ++i2)
      async16(Wb + srcOff[i2] + kh * 32, &Bs[slot][ldsOff[i2]]);
  };

  auto compute = [&](int slot) {
    bf16x8 af[8], bf[4];
#pragma unroll
    for (int mf = 0; mf < 8; ++mf) {
      const int row = wm * 128 + mf * 16 + lo;
      const int g = hi ^ ((row >> 1) & 3);
      af[mf] = *(const bf16x8*)&As[slot][row * 32 + g * 8];
    }
#pragma unroll
    for (int nf = 0; nf < 4; ++nf) {
      const int row = wn * 64 + nf * 16 + lo;
      const int g = hi ^ ((row >> 1) & 3);
      bf[nf] = *(const bf16x8*)&Bs[slot][row * 32 + g * 8];
    }
    __builtin_amdgcn_s_setprio(1);
#pragma unroll
    for (int mf = 0; mf < 8; ++mf)
#pragma unroll
      for (int nf = 0; nf < 4; ++nf)
        acc[mf][nf] = MFMA16(af[mf], bf[nf], acc[mf][nf]);
    __builtin_amdgcn_s_setprio(0);
  };

  stageSlot(0, 0);
  stageSlot(1, 1);

  for (int kt = 0; kt < 7; ++kt) {
#pragma unroll
    for (int ph = 0; ph < 4; ++ph) {
      stageSlot((ph + 2) & 3, kt * 4 + ph + 2);
      asm volatile("s_waitcnt vmcnt(8)" ::: "memory");
      __builtin_amdgcn_s_barrier();
      compute(ph);
    }
  }
  stageSlot(2, 30);
  asm volatile("s_waitcnt vmcnt(8)" ::: "memory");
  __builtin_amdgcn_s_barrier();
  compute(0);
  stageSlot(3, 31);
  asm volatile("s_waitcnt vmcnt(8)" ::: "memory");
  __builtin_amdgcn_s_barrier();
  compute(1);
  asm volatile("s_waitcnt vmcnt(4)" ::: "memory");
  __builtin_amdgcn_s_barrier();
  compute(2);
  asm volatile("s_waitcnt vmcnt(0)" ::: "memory");
  __builtin_amdgcn_s_barrier();
  compute(3);

  const int rb0 = bm * 256 + wm * 128;
  const int jb0 = bn * 256 + wn * 64;

  if constexpr (EPI == 0) {
#pragma unroll
    for (int ac = 0; ac < 4; ++ac) {
      const int j = jb0 + ac * 16 + lo;
      const int which = j >> 10;        // 0=q 1=k 2=v (uniform per wave)
      const int f = j & 1023;
      const int h = f >> 6, d = f & 63; // d = ac*16+lo; d<32 <=> ac<2
#pragma unroll
      for (int ar = 0; ar < 8; ++ar) {
        const int rb = rb0 + ar * 16 + 4 * hi;
        f32x4 v = acc[ar][ac];
        if (which == 2) {
          // v transposed: vt[(b*16+h)*64 + d][n], 4 consecutive n -> 8B store
          const int b = rb >> 10, n0 = rb & 1023;
          bf16x4 pk = {(bf16)v[0], (bf16)v[1], (bf16)v[2], (bf16)v[3]};
          *(bf16x4*)(ovt + ((size_t)((b * 16 + h) * 64 + d)) * 1024 + n0) = pk;
        } else {
          bf16* dst = which ? okk : oq;
          const float sc = which ? 1.0f : QSCALE;
#pragma unroll
          for (int reg = 0; reg < 4; ++reg) {
            const int r2 = rb + reg;
            const int b = r2 >> 10, n = r2 & 1023;
            float val = v[reg];
            float res;
            if (d < 32) {
              float c = cosT[n * 32 + d];
              float sn = sinT[n * 32 + d];
              float pp = __shfl_xor(val, 1);  // rotary partner: adjacent lane = d^1
              res = (d & 1) ? fmaf(val, c, pp * sn) : fmaf(val, c, -(pp * sn));
            } else {
              res = val;
            }
            dst[((size_t)((b * 16 + h) * 1024 + n)) * 64 + d] = (bf16)(res * sc);
          }
        }
      }
    }
  } else {
#pragma unroll
    for (int ac = 0; ac < 4; ++ac) {
      const int j = jb0 + ac * 16 + lo;
      const float bv = bias[j];
#pragma unroll
      for (int ar = 0; ar < 8; ++ar) {
        const int rb = rb0 + ar * 16 + 4 * hi;
#pragma unroll
        for (int reg = 0; reg < 4; ++reg)
          outF[(size_t)(rb + reg) * 1024 + j] = acc[ar][ac][reg] + bv;
      }
    }
  }
}

// ---------------- flash attention v4: 64 q-rows/wave, K/V frags reused 2x -------
// 8 waves x 64 q-rows = 512 rows/block, 512 blocks. LDS-port model: R7 (32
// rows/wave) issued 16 b128 reads per 16 MFMA32 -> LDS port oversubscribed
// ~4:1 vs MFMA. Here each K/V fragment feeds TWO row-sets: 16 reads per 32
// MFMAs -> LDS clk per unit work halved. Needs (512,2) reg budget (peak ~190:
// z 4x16 + of 4x16 + qf 32 + packs; (512,4)'s 128 cap would spill — R3 lesson).
// Same verified staging (global_load_lds, XOR swizzle g^(row&7), measured 0
// conflicts), 2-slot double buffer, counted vmcnt(2), one trailing
// __syncthreads per iter (WAR-safe: reads of slot cur drain before the wave's
// own barrier, which precedes the next iter's stage of that slot).
// Swapped QK^T (mfma(K,Q)): P lane-local, in-register (cvt_pk + permlane32),
// no Pt round-trip; psum per-lane scalar, one shfl_xor(32) at the end.
__global__ __launch_bounds__(512, 2) void attn_fwd(const bf16* __restrict__ q,
                                                   const bf16* __restrict__ k,
                                                   const bf16* __restrict__ vt,
                                                   bf16* __restrict__ o) {
  __shared__ bf16 Kt[2][64 * 64];
  __shared__ bf16 Vt[2][64 * 64];
  __shared__ float Psm[8][64];
  const int tid = threadIdx.x;
  const int lane = tid & 63, wid = tid >> 6;
  const int l31 = lane & 31;
  const int s = lane >> 5;          // half-wave index
  const int m7 = l31 & 7;
  // XCD-aware mapping: both q-tiles of head bh land on XCD (bh&7)
  const int j = blockIdx.x;                  // 0..511
  const int bh = (j & 7) + ((j >> 4) << 3);  // 0..255
  const int qt = (j >> 3) & 1;               // 0..1
  const bf16* qg = q + (size_t)bh * 65536;
  const bf16* kg = k + (size_t)bh * 65536;
  const bf16* vg = vt + (size_t)bh * 65536;

  // Q as B-frags, 2 row-sets: qf[rs][kb4] elem j = Q[qrow][16*kb4 + 8*s + j]
  bf16x8 qf[2][4];
#pragma unroll
  for (int rs = 0; rs < 2; ++rs) {
    const int qrow = qt * 512 + wid * 64 + rs * 32 + l31;
#pragma unroll
    for (int kb4 = 0; kb4 < 4; ++kb4)
      qf[rs][kb4] = *(const bf16x8*)(qg + (size_t)qrow * 64 + kb4 * 16 + s * 8);
  }

  const int srow = tid >> 3;
  const int sgsrc = (tid & 7) ^ (srow & 7);
  auto stageKV = [&](int buf, int kv) {
    async16(kg + (size_t)(kv * 64 + srow) * 64 + sgsrc * 8, &Kt[buf][tid * 8]);
    async16(vg + (size_t)srow * 1024 + kv * 64 + sgsrc * 8, &Vt[buf][tid * 8]);
  };

  // drain qf loads so the async vmcnt bookkeeping below is exact
  asm volatile("s_waitcnt vmcnt(0)" ::: "memory");
  stageKV(0, 0);

  const f32x16 z16 = {0.f, 0.f, 0.f, 0.f, 0.f, 0.f, 0.f, 0.f,
                      0.f, 0.f, 0.f, 0.f, 0.f, 0.f, 0.f, 0.f};
  f32x16 of00 = z16, of01 = z16, of10 = z16, of11 = z16;  // [rs][dblock]
  float psum0 = 0.f, psum1 = 0.f;

  for (int kv = 0; kv < 16; ++kv) {
    const int cur = kv & 1;
    if (kv < 15) {
      stageKV(cur ^ 1, kv + 1);
      asm volatile("s_waitcnt vmcnt(2)" ::: "memory");
    } else {
      asm volatile("s_waitcnt vmcnt(0)" ::: "memory");
    }
    __builtin_amdgcn_s_barrier();

    // S^T = K Q (swapped): z[rs][keyblock]; K frags read ONCE, used by both rs
    f32x16 z00 = z16, z01 = z16, z10 = z16, z11 = z16;
#pragma unroll
    for (int kb4 = 0; kb4 < 4; ++kb4) {
      bf16x8 k0 = *(const bf16x8*)&Kt[cur][l31 * 64 + (((2 * kb4 + s) ^ m7) * 8)];
      bf16x8 k1 = *(const bf16x8*)&Kt[cur][(32 + l31) * 64 + (((2 * kb4 + s) ^ m7) * 8)];
      z00 = MFMA32(k0, qf[0][kb4], z00);
      z01 = MFMA32(k1, qf[0][kb4], z01);
      z10 = MFMA32(k0, qf[1][kb4], z10);
      z11 = MFMA32(k1, qf[1][kb4], z11);
    }

    // P = exp2(S^T) in-register; pack pairs (regs 2m,2m+1 = consecutive keys)
    uint c00[8], c01[8], c10[8], c11[8];
#pragma unroll
    for (int m = 0; m < 8; ++m) {
      float a, b;
      a = __builtin_amdgcn_exp2f(z00[2 * m]); b = __builtin_amdgcn_exp2f(z00[2 * m + 1]);
      psum0 += a + b; c00[m] = pkbf(a, b);
      a = __builtin_amdgcn_exp2f(z01[2 * m]); b = __builtin_amdgcn_exp2f(z01[2 * m + 1]);
      psum0 += a + b; c01[m] = pkbf(a, b);
      a = __builtin_amdgcn_exp2f(z10[2 * m]); b = __builtin_amdgcn_exp2f(z10[2 * m + 1]);
      psum1 += a + b; c10[m] = pkbf(a, b);
      a = __builtin_amdgcn_exp2f(z11[2 * m]); b = __builtin_amdgcn_exp2f(z11[2 * m + 1]);
      psum1 += a + b; c11[m] = pkbf(a, b);
    }

    // O += P V: per 16-key block, V frags read ONCE, used by both row-sets
    auto pv2 = [&](const uint* cA, const uint* cB, int bb, int kb) {
      bf16x8 vb0 = *(const bf16x8*)&Vt[cur][l31 * 64 + (((2 * kb + s) ^ m7) * 8)];
      bf16x8 vb1 = *(const bf16x8*)&Vt[cur][(32 + l31) * 64 + (((2 * kb + s) ^ m7) * 8)];
      uint w0 = cA[4 * bb], w2 = cA[4 * bb + 2];
      uint w1 = cA[4 * bb + 1], w3 = cA[4 * bb + 3];
      pls(w0, w2);
      pls(w1, w3);
      uint32x4 WA = {w0, w1, w2, w3};
      bf16x8 apv0 = __builtin_bit_cast(bf16x8, WA);
      of00 = MFMA32(apv0, vb0, of00);
      of01 = MFMA32(apv0, vb1, of01);
      uint y0 = cB[4 * bb], y2 = cB[4 * bb + 2];
      uint y1 = cB[4 * bb + 1], y3 = cB[4 * bb + 3];
      pls(y0, y2);
      pls(y1, y3);
      uint32x4 WB = {y0, y1, y2, y3};
      bf16x8 apv1 = __builtin_bit_cast(bf16x8, WB);
      of10 = MFMA32(apv1, vb0, of10);
      of11 = MFMA32(apv1, vb1, of11);
    };
    pv2(c00, c10, 0, 0);
    pv2(c00, c10, 1, 1);
    pv2(c01, c11, 0, 2);
    pv2(c01, c11, 1, 3);

    __syncthreads();  // all waves done reading cur before next stage overwrites
  }

  // psum: lane l and l+32 hold partials for the same q = l&31 (per row-set)
  psum0 += __shfl_xor(psum0, 32);
  psum1 += __shfl_xor(psum1, 32);
  if (lane < 32) {
    Psm[wid][l31] = 1.0f / psum0;
    Psm[wid][32 + l31] = 1.0f / psum1;
  }
  __syncthreads();

  // write attnout as (b, n, h*64+d) bf16; C/D row r -> q = (r&3)+8*(r>>2)+4*s
  const int b = bh >> 4, h = bh & 15;
#pragma unroll
  for (int rs = 0; rs < 2; ++rs) {
#pragma unroll
    for (int r = 0; r < 16; ++r) {
      const int qr = (r & 3) + 8 * (r >> 2) + 4 * s;
      const float iv = Psm[wid][rs * 32 + qr];
      const int n = qt * 512 + wid * 64 + rs * 32 + qr;
      const size_t base = ((size_t)(b * 1024 + n)) * 1024 + h * 64 + l31;
      if (rs == 0) {
        o[base] = (bf16)(of00[r] * iv);
        o[base + 32] = (bf16)(of01[r] * iv);
      } else {
        o[base] = (bf16)(of10[r] * iv);
        o[base + 32] = (bf16)(of11[r] * iv);
      }
    }
  }
}

extern "C" void kernel_launch(void* const* d_in, const int* in_sizes, int n_in,
                              void* d_out, int out_size, void* d_ws, size_t ws_size,
                              hipStream_t stream) {
  (void)in_sizes; (void)n_in; (void)out_size; (void)ws_size;
  const float* x = (const float*)d_in[0];
  const float* wqkv = (const float*)d_in[1];
  const float* wproj = (const float*)d_in[2];
  const float* bproj = (const float*)d_in[3];

  char* ws = (char*)d_ws;
  bf16* xb = (bf16*)(ws);                  // 33554432 B (x bf16; reused as attnout)
  bf16* wqb = (bf16*)(ws + 33554432);      // 6291456 B
  bf16* wpb = (bf16*)(ws + 39845888);      // 2097152 B
  float* cosT = (float*)(ws + 41943040);   // 131072 B
  float* sinT = (float*)(ws + 42074112);   // 131072 B
  bf16* qb = (bf16*)(ws + 42205184);       // 33554432 B  (b,h,n,d), pre-scaled
  bf16* kb = (bf16*)(ws + 75759616);       // 33554432 B  (b,h,n,d)
  bf16* vtb = (bf16*)(ws + 109314048);     // 33554432 B  (b,h,d,n)
  // total ws use: 142868480 B

  // all three f32->bf16 conversions in one launch: 5M threads
  f2b_all_kernel<<<20480, 256, 0, stream>>>(x, wqkv, wproj, xb, wqb, wpb);
  table_kernel<<<128, 256, 0, stream>>>(cosT, sinT);

  // QKV: M=16384, N=3072, K=1024 -> 64 bm x 12 bn = 768 blocks of 256x256
  gemm_bt<0, 12><<<768, 512, 0, stream>>>(xb, wqb, qb, kb, vtb, cosT, sinT,
                                          nullptr, nullptr);
  // attention: 512 blocks (2 q-tiles x 256 heads, XCD-chunked), 8 waves each
  attn_fwd<<<512, 512, 0, stream>>>(qb, kb, vtb, xb);
  // proj: M=16384, N=1024, K=1024 -> 64 bm x 4 bn = 256 blocks
  gemm_bt<1, 4><<<256, 512, 0, stream>>>(xb, wpb, nullptr, nullptr, nullptr,
                                         nullptr, nullptr, (float*)d_out, bproj);
}

// Round 11
// 250.542 us; speedup vs baseline: 1.0550x; 1.0304x over previous
//
#include <hip/hip_runtime.h>
#include <hip/hip_bf16.h>
#include <math.h>

typedef __bf16 bf16;
typedef bf16 bf16x2 __attribute__((ext_vector_type(2)));
typedef bf16 bf16x4 __attribute__((ext_vector_type(4)));
typedef bf16 bf16x8 __attribute__((ext_vector_type(8)));
typedef float f32x4 __attribute__((ext_vector_type(4)));
typedef float f32x16 __attribute__((ext_vector_type(16)));
typedef unsigned int uint;
typedef uint uint32x4 __attribute__((ext_vector_type(4)));

#define MFMA16(a, b, c) __builtin_amdgcn_mfma_f32_16x16x32_bf16((a), (b), (c), 0, 0, 0)
#define MFMA32(a, b, c) __builtin_amdgcn_mfma_f32_32x32x16_bf16((a), (b), (c), 0, 0, 0)

// q pre-scale: 1/sqrt(64) * log2(e), folded into QKV epilogue so attention
// can use raw v_exp_f32 (exp2) with no per-score multiply.
#define QSCALE 0.18033688011112042f

// async global->LDS, 16B per lane. LDS dest is wave-uniform base + lane*16
// (linear); global src is per-lane (carries the swizzle).
__device__ __forceinline__ void async16(const void* g, void* l) {
  __builtin_amdgcn_global_load_lds(
      (const __attribute__((address_space(1))) void*)g,
      (__attribute__((address_space(3))) void*)l, 16, 0, 0);
}

// pack 2 f32 -> bf16x2 word (compiler fuses to v_cvt_pk_bf16_f32)
__device__ __forceinline__ uint pkbf(float a, float b) {
  bf16x2 t = {(bf16)a, (bf16)b};
  return __builtin_bit_cast(uint, t);
}

// v_permlane32_swap_b32: x' = (lane<32 ? x : y_from_lane-32);
//                        y' = (lane<32 ? x_from_lane+32 : y)
__device__ __forceinline__ void pls(uint& x, uint& y) {
  asm volatile("v_permlane32_swap_b32 %0, %1" : "+v"(x), "+v"(y));
}

// ---------------- prep: all three f32->bf16 conversions + RoPE table ----------
// ranges (thread t): [0,4194304) x (x4 elems), [4194304,4980736) wqkv,
// [4980736,5242880) wproj, [5242880,5275648) cos/sin table (1 elem each).
__global__ __launch_bounds__(256) void prep_kernel(const float* __restrict__ x,
                                                   const float* __restrict__ wqkv,
                                                   const float* __restrict__ wproj,
                                                   bf16* __restrict__ xb,
                                                   bf16* __restrict__ wqb,
                                                   bf16* __restrict__ wpb,
                                                   float* __restrict__ cosT,
                                                   float* __restrict__ sinT) {
  int t = blockIdx.x * 256 + threadIdx.x;  // 0 .. 5275647
  if (t >= 5242880) {
    int idx = t - 5242880;  // 0..32767
    int n = idx >> 5, d = idx & 31;
    int hf = n >> 5, wf = n & 31;
    int bi = (d & 15) >> 1;
    float base = (1.0f + 73.0f * bi) * 3.14159265358979323846f;  // linspace(1,512,8)[i]*pi
    int p = (d < 16) ? hf : wf;
    float pos = (2.0f * (float)p - 31.0f) * (1.0f / 31.0f);      // linspace(-1,1,32)
    float f = pos * base;
    cosT[idx] = cosf(f);
    sinT[idx] = sinf(f);
    return;
  }
  const float* in;
  bf16* out;
  int i;
  if (t < 4194304) {            // x: 16M elems
    in = x; out = xb; i = t * 4;
  } else if (t < 4980736) {     // wqkv: 3M elems
    in = wqkv; out = wqb; i = (t - 4194304) * 4;
  } else {                      // wproj: 1M elems
    in = wproj; out = wpb; i = (t - 4980736) * 4;
  }
  f32x4 v = *(const f32x4*)(in + i);
  bf16x4 o = {(bf16)v[0], (bf16)v[1], (bf16)v[2], (bf16)v[3]};
  *(bf16x4*)(out + i) = o;
}

// ---------------- 256x256 8-wave GEMM, 32-phase counted-vmcnt pipeline ----------
// VERIFIED BEST (R4/R6/R7/R10: QKV 127.8us, MfmaUtil 34%, VGPR 112, conflicts 0).
// Session A/B history: R3 (512,4) spills acc -> 12x slowdown. R5 8-phase port
// regressed (K=1024 too short). R8 2-slot/1-barrier raced (WAR). R9 2-slot/
// 2-barrier BK=64 = 140us. GEMM K-loop structurally plateaued — do not touch.
template <int EPI, int NBN>
__global__ __launch_bounds__(512, 2) void gemm_bt(
    const bf16* __restrict__ A, const bf16* __restrict__ W,
    bf16* __restrict__ oq, bf16* __restrict__ okk, bf16* __restrict__ ovt,
    const float* __restrict__ cosT, const float* __restrict__ sinT,
    float* __restrict__ outF, const float* __restrict__ bias) {
  constexpr int K = 1024;
  __shared__ bf16 As[4][256 * 32];
  __shared__ bf16 Bs[4][256 * 32];

  const int tid = threadIdx.x;
  const int lane = tid & 63;
  const int wid = tid >> 6;          // 0..7
  const int lo = lane & 15, hi = lane >> 4;
  const int wm = wid >> 2;           // 0..1 (M half)
  const int wn = wid & 3;            // 0..3 (N quarter)

  // XCD-stripe block mapping with 4x4 square ordering inside the stripe.
  const int wg = blockIdx.x;
  const int xcd = wg & 7;
  const int i = wg >> 3;             // 0 .. 8*NBN-1
  const int s = i >> 4;              // square index
  const int r = i & 15;
  const int bm = xcd * 8 + (s & 1) * 4 + (r & 3);
  const int bn = (s >> 1) * 4 + (r >> 2);

  const bf16* Ab = A + (size_t)bm * 256 * K;
  const bf16* Wb = W + (size_t)bn * 256 * K;

  const f32x4 fzero = {0.f, 0.f, 0.f, 0.f};
  f32x4 acc[8][4];
#pragma unroll
  for (int i2 = 0; i2 < 8; ++i2)
#pragma unroll
    for (int j = 0; j < 4; ++j) acc[i2][j] = fzero;

  size_t srcOff[2];
  int ldsOff[2];
#pragma unroll
  for (int i2 = 0; i2 < 2; ++i2) {
    const int c = i2 * 512 + tid;
    const int row = c >> 2, g = c & 3;
    const int gsrc = g ^ ((row >> 1) & 3);
    srcOff[i2] = (size_t)row * K + gsrc * 8;
    ldsOff[i2] = c * 8;
  }

  auto stageSlot = [&](int slot, int kh) {
#pragma unroll
    for (int i2 = 0; i2 < 2; ++i2)
      async16(Ab + srcOff[i2] + kh * 32, &As[slot][ldsOff[i2]]);
#pragma unroll
    for (int i2 = 0; i2 < 2; ++i2)
      async16(Wb + srcOff[i2] + kh * 32, &Bs[slot][ldsOff[i2]]);
  };

  auto compute = [&](int slot) {
    bf16x8 af[8], bf[4];
#pragma unroll
    for (int mf = 0; mf < 8; ++mf) {
      const int row = wm * 128 + mf * 16 + lo;
      const int g = hi ^ ((row >> 1) & 3);
      af[mf] = *(const bf16x8*)&As[slot][row * 32 + g * 8];
    }
#pragma unroll
    for (int nf = 0; nf < 4; ++nf) {
      const int row = wn * 64 + nf * 16 + lo;
      const int g = hi ^ ((row >> 1) & 3);
      bf[nf] = *(const bf16x8*)&Bs[slot][row * 32 + g * 8];
    }
    __builtin_amdgcn_s_setprio(1);
#pragma unroll
    for (int mf = 0; mf < 8; ++mf)
#pragma unroll
      for (int nf = 0; nf < 4; ++nf)
        acc[mf][nf] = MFMA16(af[mf], bf[nf], acc[mf][nf]);
    __builtin_amdgcn_s_setprio(0);
  };

  stageSlot(0, 0);
  stageSlot(1, 1);

  for (int kt = 0; kt < 7; ++kt) {
#pragma unroll
    for (int ph = 0; ph < 4; ++ph) {
      stageSlot((ph + 2) & 3, kt * 4 + ph + 2);
      asm volatile("s_waitcnt vmcnt(8)" ::: "memory");
      __builtin_amdgcn_s_barrier();
      compute(ph);
    }
  }
  stageSlot(2, 30);
  asm volatile("s_waitcnt vmcnt(8)" ::: "memory");
  __builtin_amdgcn_s_barrier();
  compute(0);
  stageSlot(3, 31);
  asm volatile("s_waitcnt vmcnt(8)" ::: "memory");
  __builtin_amdgcn_s_barrier();
  compute(1);
  asm volatile("s_waitcnt vmcnt(4)" ::: "memory");
  __builtin_amdgcn_s_barrier();
  compute(2);
  asm volatile("s_waitcnt vmcnt(0)" ::: "memory");
  __builtin_amdgcn_s_barrier();
  compute(3);

  const int rb0 = bm * 256 + wm * 128;
  const int jb0 = bn * 256 + wn * 64;

  if constexpr (EPI == 0) {
#pragma unroll
    for (int ac = 0; ac < 4; ++ac) {
      const int j = jb0 + ac * 16 + lo;
      const int which = j >> 10;        // 0=q 1=k 2=v (uniform per wave)
      const int f = j & 1023;
      const int h = f >> 6, d = f & 63; // d = ac*16+lo; d<32 <=> ac<2
#pragma unroll
      for (int ar = 0; ar < 8; ++ar) {
        const int rb = rb0 + ar * 16 + 4 * hi;
        f32x4 v = acc[ar][ac];
        if (which == 2) {
          // v transposed: vt[(b*16+h)*64 + d][n], 4 consecutive n -> 8B store
          const int b = rb >> 10, n0 = rb & 1023;
          bf16x4 pk = {(bf16)v[0], (bf16)v[1], (bf16)v[2], (bf16)v[3]};
          *(bf16x4*)(ovt + ((size_t)((b * 16 + h) * 64 + d)) * 1024 + n0) = pk;
        } else {
          bf16* dst = which ? okk : oq;
          const float sc = which ? 1.0f : QSCALE;
#pragma unroll
          for (int reg = 0; reg < 4; ++reg) {
            const int r2 = rb + reg;
            const int b = r2 >> 10, n = r2 & 1023;
            float val = v[reg];
            float res;
            if (d < 32) {
              float c = cosT[n * 32 + d];
              float sn = sinT[n * 32 + d];
              float pp = __shfl_xor(val, 1);  // rotary partner: adjacent lane = d^1
              res = (d & 1) ? fmaf(val, c, pp * sn) : fmaf(val, c, -(pp * sn));
            } else {
              res = val;
            }
            dst[((size_t)((b * 16 + h) * 1024 + n)) * 64 + d] = (bf16)(res * sc);
          }
        }
      }
    }
  } else {
#pragma unroll
    for (int ac = 0; ac < 4; ++ac) {
      const int j = jb0 + ac * 16 + lo;
      const float bv = bias[j];
#pragma unroll
      for (int ar = 0; ar < 8; ++ar) {
        const int rb = rb0 + ar * 16 + 4 * hi;
#pragma unroll
        for (int reg = 0; reg < 4; ++reg)
          outF[(size_t)(rb + reg) * 1024 + j] = acc[ar][ac][reg] + bv;
      }
    }
  }
}

// ---------------- flash attention v3: 32x32 MFMA, swapped QK^T, P in registers --
// VERIFIED BEST (R7: total 273->254us). R10's v4 (64 q-rows/wave, 2x K/V frag
// reuse) regressed to ~70us: of+z+qf ~200 VGPR caps occupancy at 2 waves/SIMD
// vs this version's 4 — TLP loss beat the LDS-read savings (LDS port is only
// ~42% busy here, not the hard bound). 32-row/wave structure is the optimum.
__global__ __launch_bounds__(512, 4) void attn_fwd(const bf16* __restrict__ q,
                                                   const bf16* __restrict__ k,
                                                   const bf16* __restrict__ vt,
                                                   bf16* __restrict__ o) {
  __shared__ bf16 Kt[2][64 * 64];
  __shared__ bf16 Vt[2][64 * 64];
  __shared__ float Psm[8][32];
  const int tid = threadIdx.x;
  const int lane = tid & 63, wid = tid >> 6;
  const int l31 = lane & 31;
  const int s = lane >> 5;          // half-wave index
  const int m7 = l31 & 7;
  // XCD-aware mapping: all 4 q-tiles of head bh land on XCD (bh&7)
  const int j = blockIdx.x;                  // 0..1023
  const int bh = (j & 7) + ((j >> 5) << 3);  // 0..255
  const int qt = (j >> 3) & 3;               // 0..3
  const bf16* qg = q + (size_t)bh * 65536;
  const bf16* kg = k + (size_t)bh * 65536;
  const bf16* vg = vt + (size_t)bh * 65536;

  // Q as B-frags: qf[kb4] elem j = Q[qrow][16*kb4 + 8*s + j]
  const int qrow = qt * 256 + wid * 32 + l31;
  bf16x8 qf[4];
#pragma unroll
  for (int kb4 = 0; kb4 < 4; ++kb4)
    qf[kb4] = *(const bf16x8*)(qg + (size_t)qrow * 64 + kb4 * 16 + s * 8);

  const int srow = tid >> 3;
  const int sgsrc = (tid & 7) ^ (srow & 7);
  auto stageKV = [&](int buf, int kv) {
    async16(kg + (size_t)(kv * 64 + srow) * 64 + sgsrc * 8, &Kt[buf][tid * 8]);
    async16(vg + (size_t)srow * 1024 + kv * 64 + sgsrc * 8, &Vt[buf][tid * 8]);
  };

  // drain qf loads so the async vmcnt bookkeeping below is exact
  asm volatile("s_waitcnt vmcnt(0)" ::: "memory");
  stageKV(0, 0);

  f32x16 of0 = {0.f, 0.f, 0.f, 0.f, 0.f, 0.f, 0.f, 0.f,
                0.f, 0.f, 0.f, 0.f, 0.f, 0.f, 0.f, 0.f};
  f32x16 of1 = of0;
  float psum = 0.f;

  for (int kv = 0; kv < 16; ++kv) {
    const int cur = kv & 1;
    if (kv < 15) {
      stageKV(cur ^ 1, kv + 1);
      asm volatile("s_waitcnt vmcnt(2)" ::: "memory");
    } else {
      asm volatile("s_waitcnt vmcnt(0)" ::: "memory");
    }
    __builtin_amdgcn_s_barrier();

    // S^T = K Q (swapped): z0 = keys 0..31, z1 = keys 32..63 (this tile)
    f32x16 z0 = {0.f, 0.f, 0.f, 0.f, 0.f, 0.f, 0.f, 0.f,
                 0.f, 0.f, 0.f, 0.f, 0.f, 0.f, 0.f, 0.f};
    f32x16 z1 = z0;
#pragma unroll
    for (int kb4 = 0; kb4 < 4; ++kb4) {
      bf16x8 k0 = *(const bf16x8*)&Kt[cur][l31 * 64 + (((2 * kb4 + s) ^ m7) * 8)];
      bf16x8 k1 = *(const bf16x8*)&Kt[cur][(32 + l31) * 64 + (((2 * kb4 + s) ^ m7) * 8)];
      z0 = MFMA32(k0, qf[kb4], z0);
      z1 = MFMA32(k1, qf[kb4], z1);
    }

    // P = exp2(S^T) in-register; pack pairs (regs 2m,2m+1 = consecutive keys)
    uint c0[8], c1[8];
#pragma unroll
    for (int m = 0; m < 8; ++m) {
      float a0 = __builtin_amdgcn_exp2f(z0[2 * m]);
      float b0 = __builtin_amdgcn_exp2f(z0[2 * m + 1]);
      float a1 = __builtin_amdgcn_exp2f(z1[2 * m]);
      float b1 = __builtin_amdgcn_exp2f(z1[2 * m + 1]);
      psum += (a0 + b0) + (a1 + b1);
      c0[m] = pkbf(a0, b0);
      c1[m] = pkbf(a1, b1);
    }

    // O += P V: per 16-key block kb, regroup P into A-frag via 2 permlane swaps
    auto pv = [&](uint* cc, int bb, int kb) {
      uint w0 = cc[4 * bb], w2 = cc[4 * bb + 2];
      uint w1 = cc[4 * bb + 1], w3 = cc[4 * bb + 3];
      pls(w0, w2);
      pls(w1, w3);
      uint32x4 W = {w0, w1, w2, w3};
      bf16x8 apv = __builtin_bit_cast(bf16x8, W);
      bf16x8 vb0 = *(const bf16x8*)&Vt[cur][l31 * 64 + (((2 * kb + s) ^ m7) * 8)];
      bf16x8 vb1 = *(const bf16x8*)&Vt[cur][(32 + l31) * 64 + (((2 * kb + s) ^ m7) * 8)];
      of0 = MFMA32(apv, vb0, of0);
      of1 = MFMA32(apv, vb1, of1);
    };
    pv(c0, 0, 0);
    pv(c0, 1, 1);
    pv(c1, 0, 2);
    pv(c1, 1, 3);

    __syncthreads();  // all waves done reading cur before next stage overwrites
  }

  // psum: lane l and l+32 hold partials for the same q = l&31
  psum += __shfl_xor(psum, 32);
  const float inv = 1.0f / psum;
  if (lane < 32) Psm[wid][l31] = inv;
  __syncthreads();

  // write attnout as (b, n, h*64+d) bf16; C/D row r -> q = (r&3)+8*(r>>2)+4*s
  const int b = bh >> 4, h = bh & 15;
#pragma unroll
  for (int r = 0; r < 16; ++r) {
    const int qr = (r & 3) + 8 * (r >> 2) + 4 * s;
    const float iv = Psm[wid][qr];
    const int n = qt * 256 + wid * 32 + qr;
    const size_t base = ((size_t)(b * 1024 + n)) * 1024 + h * 64 + l31;
    o[base] = (bf16)(of0[r] * iv);
    o[base + 32] = (bf16)(of1[r] * iv);
  }
}

extern "C" void kernel_launch(void* const* d_in, const int* in_sizes, int n_in,
                              void* d_out, int out_size, void* d_ws, size_t ws_size,
                              hipStream_t stream) {
  (void)in_sizes; (void)n_in; (void)out_size; (void)ws_size;
  const float* x = (const float*)d_in[0];
  const float* wqkv = (const float*)d_in[1];
  const float* wproj = (const float*)d_in[2];
  const float* bproj = (const float*)d_in[3];

  char* ws = (char*)d_ws;
  bf16* xb = (bf16*)(ws);                  // 33554432 B (x bf16; reused as attnout)
  bf16* wqb = (bf16*)(ws + 33554432);      // 6291456 B
  bf16* wpb = (bf16*)(ws + 39845888);      // 2097152 B
  float* cosT = (float*)(ws + 41943040);   // 131072 B
  float* sinT = (float*)(ws + 42074112);   // 131072 B
  bf16* qb = (bf16*)(ws + 42205184);       // 33554432 B  (b,h,n,d), pre-scaled
  bf16* kb = (bf16*)(ws + 75759616);       // 33554432 B  (b,h,n,d)
  bf16* vtb = (bf16*)(ws + 109314048);     // 33554432 B  (b,h,d,n)
  // total ws use: 142868480 B

  // conversions + RoPE table in one launch: 5275648 threads
  prep_kernel<<<20608, 256, 0, stream>>>(x, wqkv, wproj, xb, wqb, wpb, cosT, sinT);

  // QKV: M=16384, N=3072, K=1024 -> 64 bm x 12 bn = 768 blocks of 256x256
  gemm_bt<0, 12><<<768, 512, 0, stream>>>(xb, wqb, qb, kb, vtb, cosT, sinT,
                                          nullptr, nullptr);
  // attention: 1024 blocks (4 q-tiles x 256 heads, XCD-chunked), 8 waves each
  attn_fwd<<<1024, 512, 0, stream>>>(qb, kb, vtb, xb);
  // proj: M=16384, N=1024, K=1024 -> 64 bm x 4 bn = 256 blocks
  gemm_bt<1, 4><<<256, 512, 0, stream>>>(xb, wpb, nullptr, nullptr, nullptr,
                                         nullptr, nullptr, (float*)d_out, bproj);
}